// Round 4
// baseline (1307.362 us; speedup 1.0000x reference)
//
#include <hip/hip_runtime.h>
#include <hip/hip_bf16.h>

typedef __bf16 bf16;
typedef __bf16 bf16x8 __attribute__((ext_vector_type(8)));
typedef float f32x4 __attribute__((ext_vector_type(4)));

#define MFMA16(a, b, c) __builtin_amdgcn_mfma_f32_16x16x32_bf16(a, b, c, 0, 0, 0)

// B=16, H=W=128, C=192, WS=8, SHIFT=4, HEADS=6, N=64 -> nW=256/img, 4096 windows
#define SCALE_Q 0.17677669529663687f

// ---------------- K0: weight fp32->bf16 + rpb bias table expansion ----------------
__global__ __launch_bounds__(256) void prep_kernel(
    const float* __restrict__ qkv_w, const float* __restrict__ proj_w,
    const float* __restrict__ fc1_w, const float* __restrict__ fc2_w,
    const float* __restrict__ rpb,
    bf16* __restrict__ wqkv, bf16* __restrict__ wproj,
    bf16* __restrict__ wfc1, bf16* __restrict__ wfc2,
    float* __restrict__ bias_full) {
  const int i = blockIdx.x * 256 + threadIdx.x;
  if (i < 110592) wqkv[i] = (bf16)qkv_w[i];
  if (i < 36864)  wproj[i] = (bf16)proj_w[i];
  if (i < 147456) { wfc1[i] = (bf16)fc1_w[i]; wfc2[i] = (bf16)fc2_w[i]; }
  if (i < 24576) {
    const int head = i >> 12;           // [6][64][64]
    const int row = (i >> 6) & 63, col = i & 63;
    const int idx = ((row >> 3) - (col >> 3) + 7) * 15 + ((row & 7) - (col & 7) + 7);
    bias_full[i] = rpb[idx * 6 + head];
  }
}

__device__ __forceinline__ int region8(int tok, int wy, int wx) {
  const int gh = wy * 8 + (tok >> 3), gw = wx * 8 + (tok & 7);
  const int rs = (gh < 120) ? 0 : ((gh < 124) ? 1 : 2);
  const int cs = (gw < 120) ? 0 : ((gw < 124) ? 1 : 2);
  return rs * 3 + cs;
}

// ---------------- K1: whole Swin block, 1 window per 384-thread block ----------------
// LDS region map (bytes), phase-aliased:
//   [0,24576)      q_s   bf16 [6][64][32]      ph2-3
//   [24576,49152)  k_s   bf16 [6][64][32]      ph2-3
//   [49152,73728)  vT_s  bf16 [6][32][64]      ph2-3
//   [73728,99328)  a_lds bf16 [64][200]        ph1-2
//   [73728,129024) p_lds bf16 [6][64][72]      ph3a (aliases a)
//   [73728,99328)  ao_s  bf16 [64][200]        ph3b-4 (aliases p, after barrier)
//   [0,49152)      h_s   f32  [64][192]        ph4-7 (aliases q+k)
//   [73728,99328)  m_s   bf16 [64][200]        ph5-6 (aliases ao)
//   [99328,124928) g_s   bf16 [64][200]        ph6
__global__ __launch_bounds__(384, 1) void swin_block_kernel(
    const float* __restrict__ x,
    const float* __restrict__ n1g, const float* __restrict__ n1b,
    const bf16* __restrict__ wqkv, const float* __restrict__ qkv_b,
    const bf16* __restrict__ wproj, const float* __restrict__ proj_b,
    const float* __restrict__ bias_full,
    const float* __restrict__ n2g, const float* __restrict__ n2b,
    const bf16* __restrict__ wfc1, const float* __restrict__ fc1_b,
    const bf16* __restrict__ wfc2, const float* __restrict__ fc2_b,
    float* __restrict__ out) {
  __shared__ __align__(16) char smem[129024];
  bf16*  q_s  = (bf16*)(smem);
  bf16*  k_s  = (bf16*)(smem + 24576);
  bf16*  vT_s = (bf16*)(smem + 49152);
  bf16*  a_s  = (bf16*)(smem + 73728);   // pitch 200
  bf16*  p_s  = (bf16*)(smem + 73728);   // [head][64][72]
  bf16*  ao_s = (bf16*)(smem + 73728);   // pitch 200
  float* h_s  = (float*)(smem);          // pitch 192
  bf16*  m_s  = (bf16*)(smem + 73728);   // pitch 200
  bf16*  g_s  = (bf16*)(smem + 99328);   // pitch 200

  const int lane = threadIdx.x & 63, waveid = threadIdx.x >> 6;
  const int c = lane & 15, quad = lane >> 4;
  const int window = blockIdx.x;
  const int bi = window >> 8, w_in = window & 255;
  const int wy = w_in >> 4, wx = w_in & 15;
  const f32x4 fzero = {0.f, 0.f, 0.f, 0.f};

  // ---- ph1: LN1 + roll(-4,-4) gather -> a_s ----
  for (int it = 0; it < 11; it++) {
    const int n = waveid * 11 + it;
    if (n < 64) {
      const int oh = (wy * 8 + (n >> 3) + 4) & 127;
      const int ow = (wx * 8 + (n & 7) + 4) & 127;
      const float* xr = x + (size_t)(bi * 16384 + oh * 128 + ow) * 192;
      float v0 = xr[lane], v1 = xr[lane + 64], v2 = xr[lane + 128];
      float s = v0 + v1 + v2;
      float s2 = v0 * v0 + v1 * v1 + v2 * v2;
#pragma unroll
      for (int off = 1; off < 64; off <<= 1) {
        s += __shfl_xor(s, off);
        s2 += __shfl_xor(s2, off);
      }
      const float mu = s * (1.f / 192.f);
      const float rinv = rsqrtf(s2 * (1.f / 192.f) - mu * mu + 1e-5f);
      a_s[n * 200 + lane]       = (bf16)((v0 - mu) * rinv * n1g[lane]       + n1b[lane]);
      a_s[n * 200 + lane + 64]  = (bf16)((v1 - mu) * rinv * n1g[lane + 64]  + n1b[lane + 64]);
      a_s[n * 200 + lane + 128] = (bf16)((v2 - mu) * rinv * n1g[lane + 128] + n1b[lane + 128]);
    }
  }
  __syncthreads();

  // ---- ph2: qkv GEMM (wave covers 96 cols = one tensor x one head pair) ----
  {
    f32x4 acc[4][6];
#pragma unroll
    for (int i = 0; i < 4; i++)
#pragma unroll
      for (int j = 0; j < 6; j++) acc[i][j] = fzero;
#pragma unroll
    for (int ks = 0; ks < 6; ks++) {
      bf16x8 a[4], w[6];
#pragma unroll
      for (int i = 0; i < 4; i++)
        a[i] = *(const bf16x8*)&a_s[(16 * i + c) * 200 + ks * 32 + quad * 8];
#pragma unroll
      for (int j = 0; j < 6; j++)
        w[j] = *(const bf16x8*)(wqkv +
            (size_t)(waveid * 96 + 16 * j + c) * 192 + ks * 32 + quad * 8);
#pragma unroll
      for (int i = 0; i < 4; i++)
#pragma unroll
        for (int j = 0; j < 6; j++) acc[i][j] = MFMA16(a[i], w[j], acc[i][j]);
    }
    const int which = waveid >> 1;   // 0=q 1=k 2=v (wave-uniform)
#pragma unroll
    for (int j = 0; j < 6; j++) {
      const int col = waveid * 96 + 16 * j + c;
      const int sub = col - which * 192;
      const int head = sub >> 5, d = sub & 31;
      const float bias = qkv_b[col];
#pragma unroll
      for (int i = 0; i < 4; i++)
#pragma unroll
        for (int r = 0; r < 4; r++) {
          const int n = 16 * i + 4 * quad + r;
          const float val = acc[i][j][r] + bias;
          if (which == 0)      q_s[head * 2048 + n * 32 + d] = (bf16)(val * SCALE_Q);
          else if (which == 1) k_s[head * 2048 + n * 32 + d] = (bf16)val;
          else                 vT_s[head * 2048 + d * 64 + n] = (bf16)val;
        }
    }
  }
  __syncthreads();

  // ---- ph3: attention, wave = head ----
  f32x4 o[4][2];
  {
    const int head = waveid;
    bf16x8 aq[4], bk[4];
#pragma unroll
    for (int i = 0; i < 4; i++)
      aq[i] = *(const bf16x8*)&q_s[head * 2048 + (16 * i + c) * 32 + quad * 8];
#pragma unroll
    for (int j = 0; j < 4; j++)
      bk[j] = *(const bf16x8*)&k_s[head * 2048 + (16 * j + c) * 32 + quad * 8];
    f32x4 s[4][4];
#pragma unroll
    for (int i = 0; i < 4; i++)
#pragma unroll
      for (int j = 0; j < 4; j++) s[i][j] = fzero;
#pragma unroll
    for (int i = 0; i < 4; i++)
#pragma unroll
      for (int j = 0; j < 4; j++) s[i][j] = MFMA16(aq[i], bk[j], s[i][j]);

    const float* bfp = bias_full + head * 4096;
#pragma unroll
    for (int i = 0; i < 4; i++)
#pragma unroll
      for (int r = 0; r < 4; r++) {
        const int row = 16 * i + 4 * quad + r;
#pragma unroll
        for (int j = 0; j < 4; j++) s[i][j][r] += bfp[row * 64 + 16 * j + c];
      }

    if (wy == 15 || wx == 15) {
      int creg[4];
#pragma unroll
      for (int j = 0; j < 4; j++) creg[j] = region8(16 * j + c, wy, wx);
#pragma unroll
      for (int i = 0; i < 4; i++)
#pragma unroll
        for (int r = 0; r < 4; r++) {
          const int rreg = region8(16 * i + 4 * quad + r, wy, wx);
#pragma unroll
          for (int j = 0; j < 4; j++)
            if (rreg != creg[j]) s[i][j][r] -= 100.f;
        }
    }

    // softmax per row; write P into own head's p_s (own-wave RAW, no barrier)
#pragma unroll
    for (int i = 0; i < 4; i++)
#pragma unroll
      for (int r = 0; r < 4; r++) {
        float mx = fmaxf(fmaxf(s[i][0][r], s[i][1][r]), fmaxf(s[i][2][r], s[i][3][r]));
#pragma unroll
        for (int off = 1; off < 16; off <<= 1) mx = fmaxf(mx, __shfl_xor(mx, off));
        float sum = 0.f;
#pragma unroll
        for (int j = 0; j < 4; j++) {
          const float p = __expf(s[i][j][r] - mx);
          s[i][j][r] = p;
          sum += p;
        }
#pragma unroll
        for (int off = 1; off < 16; off <<= 1) sum += __shfl_xor(sum, off);
        const float inv = 1.f / sum;
        const int row = 16 * i + 4 * quad + r;
#pragma unroll
        for (int j = 0; j < 4; j++)
          p_s[head * 4608 + row * 72 + 16 * j + c] = (bf16)(s[i][j][r] * inv);
      }

    // O = P @ V
#pragma unroll
    for (int i = 0; i < 4; i++)
#pragma unroll
      for (int tn = 0; tn < 2; tn++) o[i][tn] = fzero;
#pragma unroll
    for (int ks = 0; ks < 2; ks++) {
      bf16x8 ap[4], bv[2];
#pragma unroll
      for (int i = 0; i < 4; i++)
        ap[i] = *(const bf16x8*)&p_s[head * 4608 + (16 * i + c) * 72 + ks * 32 + quad * 8];
#pragma unroll
      for (int tn = 0; tn < 2; tn++)
        bv[tn] = *(const bf16x8*)&vT_s[head * 2048 + (16 * tn + c) * 64 + ks * 32 + quad * 8];
#pragma unroll
      for (int i = 0; i < 4; i++)
#pragma unroll
        for (int tn = 0; tn < 2; tn++) o[i][tn] = MFMA16(ap[i], bv[tn], o[i][tn]);
    }
  }
  __syncthreads();   // all p_s reads done before ao_s overwrites the region

  // attn_out -> ao_s [64][200]
#pragma unroll
  for (int i = 0; i < 4; i++)
#pragma unroll
    for (int tn = 0; tn < 2; tn++)
#pragma unroll
      for (int r = 0; r < 4; r++)
        ao_s[(16 * i + 4 * quad + r) * 200 + waveid * 32 + 16 * tn + c] = (bf16)o[i][tn][r];
  __syncthreads();

  // ---- ph4: proj GEMM + shortcut residual -> h_s (fp32) ----
  {
    f32x4 acc[4][2];
#pragma unroll
    for (int i = 0; i < 4; i++)
#pragma unroll
      for (int j = 0; j < 2; j++) acc[i][j] = fzero;
#pragma unroll
    for (int ks = 0; ks < 6; ks++) {
      bf16x8 a[4], w[2];
#pragma unroll
      for (int i = 0; i < 4; i++)
        a[i] = *(const bf16x8*)&ao_s[(16 * i + c) * 200 + ks * 32 + quad * 8];
#pragma unroll
      for (int j = 0; j < 2; j++)
        w[j] = *(const bf16x8*)(wproj +
            (size_t)(waveid * 32 + 16 * j + c) * 192 + ks * 32 + quad * 8);
#pragma unroll
      for (int i = 0; i < 4; i++)
#pragma unroll
        for (int j = 0; j < 2; j++) acc[i][j] = MFMA16(a[i], w[j], acc[i][j]);
    }
#pragma unroll
    for (int i = 0; i < 4; i++)
#pragma unroll
      for (int r = 0; r < 4; r++) {
        const int n = 16 * i + 4 * quad + r;
        const int oh = (wy * 8 + (n >> 3) + 4) & 127;
        const int ow = (wx * 8 + (n & 7) + 4) & 127;
        const float* xr = x + (size_t)(bi * 16384 + oh * 128 + ow) * 192;
#pragma unroll
        for (int j = 0; j < 2; j++) {
          const int col = waveid * 32 + 16 * j + c;
          h_s[n * 192 + col] = acc[i][j][r] + proj_b[col] + xr[col];
        }
      }
  }
  __syncthreads();

  // ---- ph5: LN2 -> m_s ----
  for (int it = 0; it < 11; it++) {
    const int n = waveid * 11 + it;
    if (n < 64) {
      float v0 = h_s[n * 192 + lane], v1 = h_s[n * 192 + lane + 64],
            v2 = h_s[n * 192 + lane + 128];
      float s = v0 + v1 + v2;
      float s2 = v0 * v0 + v1 * v1 + v2 * v2;
#pragma unroll
      for (int off = 1; off < 64; off <<= 1) {
        s += __shfl_xor(s, off);
        s2 += __shfl_xor(s2, off);
      }
      const float mu = s * (1.f / 192.f);
      const float rinv = rsqrtf(s2 * (1.f / 192.f) - mu * mu + 1e-5f);
      m_s[n * 200 + lane]       = (bf16)((v0 - mu) * rinv * n2g[lane]       + n2b[lane]);
      m_s[n * 200 + lane + 64]  = (bf16)((v1 - mu) * rinv * n2g[lane + 64]  + n2b[lane + 64]);
      m_s[n * 200 + lane + 128] = (bf16)((v2 - mu) * rinv * n2g[lane + 128] + n2b[lane + 128]);
    }
  }
  __syncthreads();

  // ---- ph6: MLP fc1 -> GELU -> fc2 (4 chunks of 192) ----
  f32x4 oacc[4][2];
#pragma unroll
  for (int i = 0; i < 4; i++)
#pragma unroll
    for (int j = 0; j < 2; j++) oacc[i][j] = fzero;

  for (int chunk = 0; chunk < 4; chunk++) {
    f32x4 gacc[4][2];
#pragma unroll
    for (int i = 0; i < 4; i++)
#pragma unroll
      for (int j = 0; j < 2; j++) gacc[i][j] = fzero;
#pragma unroll
    for (int ks = 0; ks < 6; ks++) {
      bf16x8 a[4], w[2];
#pragma unroll
      for (int i = 0; i < 4; i++)
        a[i] = *(const bf16x8*)&m_s[(16 * i + c) * 200 + ks * 32 + quad * 8];
#pragma unroll
      for (int j = 0; j < 2; j++)
        w[j] = *(const bf16x8*)(wfc1 +
            (size_t)(chunk * 192 + waveid * 32 + 16 * j + c) * 192 + ks * 32 + quad * 8);
#pragma unroll
      for (int i = 0; i < 4; i++)
#pragma unroll
        for (int j = 0; j < 2; j++) gacc[i][j] = MFMA16(a[i], w[j], gacc[i][j]);
    }
#pragma unroll
    for (int i = 0; i < 4; i++)
#pragma unroll
      for (int j = 0; j < 2; j++) {
        const int lcol = waveid * 32 + 16 * j + c;
        const float fb = fc1_b[chunk * 192 + lcol];
#pragma unroll
        for (int r = 0; r < 4; r++) {
          float val = gacc[i][j][r] + fb;
          val = 0.5f * val * (1.f + erff(val * 0.70710678118654752f));
          g_s[(16 * i + 4 * quad + r) * 200 + lcol] = (bf16)val;
        }
      }
    __syncthreads();
#pragma unroll
    for (int ks = 0; ks < 6; ks++) {
      bf16x8 a[4], w[2];
#pragma unroll
      for (int i = 0; i < 4; i++)
        a[i] = *(const bf16x8*)&g_s[(16 * i + c) * 200 + ks * 32 + quad * 8];
#pragma unroll
      for (int j = 0; j < 2; j++)
        w[j] = *(const bf16x8*)(wfc2 +
            (size_t)(waveid * 32 + 16 * j + c) * 768 + chunk * 192 + ks * 32 + quad * 8);
#pragma unroll
      for (int i = 0; i < 4; i++)
#pragma unroll
        for (int j = 0; j < 2; j++) oacc[i][j] = MFMA16(a[i], w[j], oacc[i][j]);
    }
    __syncthreads();
  }

  // ---- ph7: epilogue: + fc2_b + h, un-shift scatter, fp32 out ----
#pragma unroll
  for (int i = 0; i < 4; i++)
#pragma unroll
    for (int r = 0; r < 4; r++) {
      const int n = 16 * i + 4 * quad + r;
      const int oh = (wy * 8 + (n >> 3) + 4) & 127;
      const int ow = (wx * 8 + (n & 7) + 4) & 127;
      float* orow = out + (size_t)(bi * 16384 + oh * 128 + ow) * 192;
#pragma unroll
      for (int j = 0; j < 2; j++) {
        const int col = waveid * 32 + 16 * j + c;
        orow[col] = oacc[i][j][r] + fc2_b[col] + h_s[n * 192 + col];
      }
    }
}

// ---------------- launch ----------------
extern "C" void kernel_launch(void* const* d_in, const int* in_sizes, int n_in,
                              void* d_out, int out_size, void* d_ws, size_t ws_size,
                              hipStream_t stream) {
  const float* x      = (const float*)d_in[0];
  const float* n1g    = (const float*)d_in[1];
  const float* n1b    = (const float*)d_in[2];
  const float* qkv_w  = (const float*)d_in[3];
  const float* qkv_b  = (const float*)d_in[4];
  const float* proj_w = (const float*)d_in[5];
  const float* proj_b = (const float*)d_in[6];
  const float* rpb    = (const float*)d_in[7];
  const float* n2g    = (const float*)d_in[8];
  const float* n2b    = (const float*)d_in[9];
  const float* fc1_w  = (const float*)d_in[10];
  const float* fc1_b  = (const float*)d_in[11];
  const float* fc2_w  = (const float*)d_in[12];
  const float* fc2_b  = (const float*)d_in[13];

  // tiny workspace: 983,040 B total
  char* ws = (char*)d_ws;
  float* biasf = (float*)(ws);                       // 98,304 B
  bf16*  wqkv  = (bf16*)(ws + 98304);                // 221,184 B
  bf16*  wproj = (bf16*)(ws + 98304 + 221184);       // 73,728 B
  bf16*  wfc1  = (bf16*)(ws + 98304 + 221184 + 73728);            // 294,912 B
  bf16*  wfc2  = (bf16*)(ws + 98304 + 221184 + 73728 + 294912);   // 294,912 B

  prep_kernel<<<576, 256, 0, stream>>>(qkv_w, proj_w, fc1_w, fc2_w, rpb,
                                       wqkv, wproj, wfc1, wfc2, biasf);
  swin_block_kernel<<<4096, 384, 0, stream>>>(
      x, n1g, n1b, wqkv, qkv_b, wproj, proj_b, biasf,
      n2g, n2b, wfc1, fc1_b, wfc2, fc2_b, (float*)d_out);
}